// Round 1
// baseline (1023.684 us; speedup 1.0000x reference)
//
#include <hip/hip_runtime.h>

#define BSZ   16
#define NDIM  128
#define KP1   65537
#define NDATA 1000000

__constant__ float kInvT_unused; // (not used; keep constants as literals)

// ---------------------------------------------------------------------------
// Kernel 1: full memory-bank copy  (512 MB read + 512 MB write, float4)
// ---------------------------------------------------------------------------
__global__ void copy_mem_kernel(const float4* __restrict__ src,
                                float4* __restrict__ dst, int n4) {
    int i = blockIdx.x * blockDim.x + threadIdx.x;
    if (i < n4) dst[i] = src[i];
}

// ---------------------------------------------------------------------------
// Kernel 2: EMA update + L2 renormalize for the 16 positive rows.
// One block (128 threads = 2 waves) per batch row. Runs AFTER the copy.
// ---------------------------------------------------------------------------
__global__ void ema_update_kernel(const float* __restrict__ x,
                                  const int* __restrict__ y,
                                  const float* __restrict__ memory,
                                  float* __restrict__ out_mem) {
    int b = blockIdx.x;          // 0..15
    int t = threadIdx.x;         // 0..127
    long long row = (long long)y[b];
    float w = 0.5f * memory[row * NDIM + t] + 0.5f * x[b * NDIM + t];

    // sum of squares across 128 threads (2 waves)
    float ss = w * w;
    #pragma unroll
    for (int off = 32; off > 0; off >>= 1) ss += __shfl_xor(ss, off, 64);
    __shared__ float s_partial[2];
    if ((t & 63) == 0) s_partial[t >> 6] = ss;
    __syncthreads();
    float total = s_partial[0] + s_partial[1];
    float denom = fmaxf(sqrtf(total), 1e-12f);
    out_mem[row * NDIM + t] = w / denom;
}

// ---------------------------------------------------------------------------
// Kernel 3: logits.  One wave per (b,k) row: 64 lanes x float2 = 512 B row,
// coalesced gather + wave shuffle reduction.  idx[b][0] replaced by y[b].
// Uses ORIGINAL memory (reference gathers before the EMA update).
// ---------------------------------------------------------------------------
__global__ void logits_kernel(const float* __restrict__ x,
                              const int* __restrict__ y,
                              const int* __restrict__ idx,
                              const float* __restrict__ memory,
                              float* __restrict__ logits) {
    int b    = blockIdx.y;            // 0..15
    int wave = threadIdx.x >> 6;      // 0..3
    int lane = threadIdx.x & 63;
    int k    = blockIdx.x * 4 + wave;
    if (k >= KP1) return;

    long long row = (k == 0) ? (long long)y[b]
                             : (long long)idx[(long long)b * KP1 + k];

    const float2* m2 = (const float2*)(memory + row * NDIM);
    const float2* x2 = (const float2*)(x + b * NDIM);
    float2 mv = m2[lane];
    float2 xv = x2[lane];
    float p = mv.x * xv.x + mv.y * xv.y;

    #pragma unroll
    for (int off = 32; off > 0; off >>= 1) p += __shfl_xor(p, off, 64);

    if (lane == 0) logits[(long long)b * KP1 + k] = p * (1.0f / 0.07f);
}

// ---------------------------------------------------------------------------
// Kernel 4: labels = zeros(16). (bit pattern 0 is valid as int32 or f32)
// ---------------------------------------------------------------------------
__global__ void labels_kernel(float* __restrict__ labels) {
    if (threadIdx.x < BSZ) labels[threadIdx.x] = 0.0f;
}

extern "C" void kernel_launch(void* const* d_in, const int* in_sizes, int n_in,
                              void* d_out, int out_size, void* d_ws, size_t ws_size,
                              hipStream_t stream) {
    const float* x      = (const float*)d_in[0];   // (16,128) f32
    const int*   y      = (const int*)d_in[1];     // (16,) int
    const int*   idx    = (const int*)d_in[2];     // (16,65537) int
    const float* memory = (const float*)d_in[3];   // (1e6,128) f32

    float* logits  = (float*)d_out;                       // 16*65537
    float* labels  = logits + (long long)BSZ * KP1;       // 16
    float* out_mem = labels + BSZ;                        // 1e6*128

    // 1) copy bank (must precede EMA scatter)
    int n4 = NDATA * NDIM / 4;  // 32,000,000 -> 125,000 blocks of 256
    copy_mem_kernel<<<n4 / 256, 256, 0, stream>>>(
        (const float4*)memory, (float4*)out_mem, n4);

    // 2) EMA + renorm scatter (same stream => ordered after copy)
    ema_update_kernel<<<BSZ, NDIM, 0, stream>>>(x, y, memory, out_mem);

    // 3) logits gather+dot
    dim3 grid((KP1 + 3) / 4, BSZ);
    logits_kernel<<<grid, 256, 0, stream>>>(x, y, idx, memory, logits);

    // 4) labels
    labels_kernel<<<1, 64, 0, stream>>>(labels);
}